// Round 1
// baseline (637.063 us; speedup 1.0000x reference)
//
#include <hip/hip_runtime.h>
#include <math.h>

// Problem constants (B=4, H=W=64, C=128, DI=256, N=16, R=8, K=4)
#define LL   4096     // H*W
#define DDIM 256      // d_inner
#define NCH  64       // number of chunks
#define LCH  64       // chunk length
// B*K*D = 4096 scan channels; B*K*D*N = 65536 states

__device__ __forceinline__ float silu_f(float x) {
    return x / (1.f + __expf(-x));
}
__device__ __forceinline__ float softplus_f(float x) {
    // matches jax.nn.softplus = log1p(exp(x)), stable form
    return fmaxf(x, 0.f) + __logf(1.f + __expf(-fabsf(x)));
}
__device__ __forceinline__ int perm_idx(int k, int l) {
    // spatial position read by direction k at scan step l (H=W=64)
    switch (k & 3) {
        case 0: return l;
        case 1: return ((l & 63) << 6) | (l >> 6);
        case 2: return 4095 - l;
        default: { int lr = 4095 - l; return ((lr & 63) << 6) | (lr >> 6); }
    }
}

// ---------------------------------------------------------------------------
// Generic fp32 tiled GEMM: out[m,n] = sum_k A[m,k] * W[n,k]
// EPI=0: plain store to out0[M x N]
// EPI=1: in_proj epilogue: n<256 -> xc_raw[m*256+n]; n>=256 -> z[m*256+n-256]=silu
// ---------------------------------------------------------------------------
template <int EPI>
__global__ __launch_bounds__(256) void gemm_ep(
    const float* __restrict__ A, const float* __restrict__ W,
    float* __restrict__ out0, float* __restrict__ out1,
    int M, int N, int K) {
    __shared__ float As[16][65];
    __shared__ float Ws[16][65];
    const int tid = threadIdx.x;
    const int bx = blockIdx.x, by = blockIdx.y;
    const int tx = tid & 15, ty = tid >> 4;
    const int lrow = tid >> 2;          // 0..63
    const int lk = (tid & 3) << 2;      // 0,4,8,12
    float acc[4][4] = {};
    const float* Ap = A + (size_t)(by * 64 + lrow) * K + lk;
    const int wrow = bx * 64 + lrow;
    const float* Wp = W + (size_t)wrow * K + lk;
    const bool wv = (wrow < N);
    for (int k0 = 0; k0 < K; k0 += 16) {
        float4 av = *(const float4*)(Ap + k0);
        float4 bv = make_float4(0.f, 0.f, 0.f, 0.f);
        if (wv) bv = *(const float4*)(Wp + k0);
        As[lk + 0][lrow] = av.x; As[lk + 1][lrow] = av.y;
        As[lk + 2][lrow] = av.z; As[lk + 3][lrow] = av.w;
        Ws[lk + 0][lrow] = bv.x; Ws[lk + 1][lrow] = bv.y;
        Ws[lk + 2][lrow] = bv.z; Ws[lk + 3][lrow] = bv.w;
        __syncthreads();
        #pragma unroll
        for (int kk = 0; kk < 16; ++kk) {
            float a4[4], b4[4];
            #pragma unroll
            for (int i = 0; i < 4; ++i) a4[i] = As[kk][ty * 4 + i];
            #pragma unroll
            for (int j = 0; j < 4; ++j) b4[j] = Ws[kk][tx * 4 + j];
            #pragma unroll
            for (int i = 0; i < 4; ++i)
                #pragma unroll
                for (int j = 0; j < 4; ++j)
                    acc[i][j] = fmaf(a4[i], b4[j], acc[i][j]);
        }
        __syncthreads();
    }
    #pragma unroll
    for (int i = 0; i < 4; ++i) {
        const int m = by * 64 + ty * 4 + i;
        #pragma unroll
        for (int j = 0; j < 4; ++j) {
            const int nn = bx * 64 + tx * 4 + j;
            if (nn >= N) continue;
            const float v = acc[i][j];
            if (EPI == 0) {
                out0[(size_t)m * N + nn] = v;
            } else {
                if (nn < 256) out0[(size_t)m * 256 + nn] = v;
                else          out1[(size_t)m * 256 + (nn - 256)] = silu_f(v);
            }
        }
    }
}

// ---------------------------------------------------------------------------
// Depthwise 3x3 conv (SAME, zero pad) + bias + SiLU. Layout (B*L, D) chan-last.
// ---------------------------------------------------------------------------
__global__ __launch_bounds__(256) void dwconv_silu(
    const float* __restrict__ in, const float* __restrict__ w,
    const float* __restrict__ bias, float* __restrict__ out) {
    const int d = threadIdx.x;
    const int bp = blockIdx.x;              // b*L + p
    const int b = bp >> 12;
    const int sp = bp & 4095;
    const int h = sp >> 6, wc = sp & 63;
    float acc = bias[d];
    #pragma unroll
    for (int kh = 0; kh < 3; ++kh) {
        const int hh = h + kh - 1;
        if (hh < 0 || hh >= 64) continue;
        #pragma unroll
        for (int kw = 0; kw < 3; ++kw) {
            const int ww = wc + kw - 1;
            if (ww < 0 || ww >= 64) continue;
            acc = fmaf(in[(size_t)(((b << 12) + (hh << 6) + ww)) * DDIM + d],
                       w[d * 9 + kh * 3 + kw], acc);
        }
    }
    out[(size_t)bp * DDIM + d] = silu_f(acc);
}

// ---------------------------------------------------------------------------
// Scan phase A: per-chunk local scan from h=0. Outputs h_end and decay prod P.
// block = 256 threads (d); blockIdx = ((b*4+k)*64 + chunk)
// ---------------------------------------------------------------------------
__global__ __launch_bounds__(256) void scanA(
    const float* __restrict__ xc, const float* __restrict__ proj,
    const float* __restrict__ Alogs, const float* __restrict__ dtw,
    const float* __restrict__ dtb,
    float* __restrict__ hend, float* __restrict__ Pout) {
    const int d = threadIdx.x;
    const int blk = blockIdx.x;
    const int c = blk & 63;
    const int bk = blk >> 6;          // b*4+k
    const int k = bk & 3;
    const int b = bk >> 2;
    const int kd = k * DDIM + d;

    float a[16], w8[8];
    #pragma unroll
    for (int n = 0; n < 16; ++n) a[n] = -__expf(Alogs[kd * 16 + n]);
    #pragma unroll
    for (int r = 0; r < 8; ++r) w8[r] = dtw[kd * 8 + r];
    const float bias = dtb[kd];

    float h[16], P[16];
    #pragma unroll
    for (int n = 0; n < 16; ++n) { h[n] = 0.f; P[n] = 1.f; }

    const int l0 = c * LCH;
    for (int t = 0; t < LCH; ++t) {
        const int l = l0 + t;
        const int p = perm_idx(k, l);
        const float u = xc[(size_t)((b << 12) + p) * DDIM + d];
        const float* pr = proj + (size_t)((b << 12) + p) * 160 + k * 40;
        float x = bias;
        #pragma unroll
        for (int r = 0; r < 8; ++r) x = fmaf(pr[r], w8[r], x);
        const float delta = softplus_f(x);
        const float du = delta * u;
        #pragma unroll
        for (int n = 0; n < 16; ++n) {
            const float dA = __expf(delta * a[n]);
            P[n] *= dA;
            h[n] = fmaf(dA, h[n], du * pr[8 + n]);
        }
    }
    const size_t o = ((size_t)c * 4096 + (size_t)bk * DDIM + d) * 16;
    #pragma unroll
    for (int n = 0; n < 16; ++n) { hend[o + n] = h[n]; Pout[o + n] = P[n]; }
}

// ---------------------------------------------------------------------------
// Scan phase B: inter-chunk recurrence (64 steps), 65536 states.
// ---------------------------------------------------------------------------
__global__ __launch_bounds__(256) void scanB(
    const float* __restrict__ hend, const float* __restrict__ P,
    float* __restrict__ H0) {
    const int tid = blockIdx.x * 256 + threadIdx.x;  // (bk*256+d)*16+n
    float H = 0.f;
    H0[tid] = 0.f;
    for (int c = 1; c < NCH; ++c) {
        const size_t i = (size_t)(c - 1) * 65536 + tid;
        H = fmaf(P[i], H, hend[i]);
        H0[(size_t)c * 65536 + tid] = H;
    }
}

// ---------------------------------------------------------------------------
// Scan phase C: re-run chunks from true initial state, emit y at spatial pos.
// ysp layout: [(b*4+k)*L + p] * D + d
// ---------------------------------------------------------------------------
__global__ __launch_bounds__(256) void scanC(
    const float* __restrict__ xc, const float* __restrict__ proj,
    const float* __restrict__ Alogs, const float* __restrict__ dtw,
    const float* __restrict__ dtb, const float* __restrict__ Dsv,
    const float* __restrict__ H0, float* __restrict__ ysp) {
    const int d = threadIdx.x;
    const int blk = blockIdx.x;
    const int c = blk & 63;
    const int bk = blk >> 6;
    const int k = bk & 3;
    const int b = bk >> 2;
    const int kd = k * DDIM + d;

    float a[16], w8[8];
    #pragma unroll
    for (int n = 0; n < 16; ++n) a[n] = -__expf(Alogs[kd * 16 + n]);
    #pragma unroll
    for (int r = 0; r < 8; ++r) w8[r] = dtw[kd * 8 + r];
    const float bias = dtb[kd];
    const float Dd = Dsv[kd];

    float h[16];
    const size_t ho = ((size_t)c * 4096 + (size_t)bk * DDIM + d) * 16;
    #pragma unroll
    for (int n = 0; n < 16; ++n) h[n] = H0[ho + n];

    const int l0 = c * LCH;
    for (int t = 0; t < LCH; ++t) {
        const int l = l0 + t;
        const int p = perm_idx(k, l);
        const float u = xc[(size_t)((b << 12) + p) * DDIM + d];
        const float* pr = proj + (size_t)((b << 12) + p) * 160 + k * 40;
        float x = bias;
        #pragma unroll
        for (int r = 0; r < 8; ++r) x = fmaf(pr[r], w8[r], x);
        const float delta = softplus_f(x);
        const float du = delta * u;
        float y = 0.f;
        #pragma unroll
        for (int n = 0; n < 16; ++n) {
            const float dA = __expf(delta * a[n]);
            h[n] = fmaf(dA, h[n], du * pr[8 + n]);
            y = fmaf(h[n], pr[24 + n], y);
        }
        y = fmaf(Dd, u, y);
        ysp[(size_t)((bk << 12) + p) * DDIM + d] = y;
    }
}

// ---------------------------------------------------------------------------
// Merge 4 directions + LayerNorm(D) + gate with z. One block per (b,p).
// ---------------------------------------------------------------------------
__global__ __launch_bounds__(256) void merge_ln(
    const float* __restrict__ ysp, const float* __restrict__ z,
    const float* __restrict__ lnw, const float* __restrict__ lnb,
    float* __restrict__ yz) {
    const int d = threadIdx.x;
    const int bp = blockIdx.x;        // b*L + p
    const int b = bp >> 12;
    const int p = bp & 4095;
    float v = 0.f;
    #pragma unroll
    for (int k = 0; k < 4; ++k)
        v += ysp[(size_t)((((b << 2) + k) << 12) + p) * DDIM + d];

    __shared__ float red[4];
    float s = v;
    #pragma unroll
    for (int o = 32; o > 0; o >>= 1) s += __shfl_xor(s, o);
    const int wave = threadIdx.x >> 6;
    if ((threadIdx.x & 63) == 0) red[wave] = s;
    __syncthreads();
    const float mu = (red[0] + red[1] + red[2] + red[3]) * (1.f / 256.f);
    __syncthreads();
    const float dv = v - mu;
    float s2 = dv * dv;
    #pragma unroll
    for (int o = 32; o > 0; o >>= 1) s2 += __shfl_xor(s2, o);
    if ((threadIdx.x & 63) == 0) red[wave] = s2;
    __syncthreads();
    const float var = (red[0] + red[1] + red[2] + red[3]) * (1.f / 256.f);
    const float y = dv * rsqrtf(var + 1e-5f) * lnw[d] + lnb[d];
    yz[(size_t)bp * DDIM + d] = y * z[(size_t)bp * DDIM + d];
}

// ---------------------------------------------------------------------------
extern "C" void kernel_launch(void* const* d_in, const int* in_sizes, int n_in,
                              void* d_out, int out_size, void* d_ws, size_t ws_size,
                              hipStream_t stream) {
    const float* xin[2]   = {(const float*)d_in[0],  (const float*)d_in[1]};
    const float* inw[2]   = {(const float*)d_in[2],  (const float*)d_in[3]};
    const float* convw[2] = {(const float*)d_in[4],  (const float*)d_in[6]};
    const float* convb[2] = {(const float*)d_in[5],  (const float*)d_in[7]};
    const float* xpw   = (const float*)d_in[8];
    const float* dtw   = (const float*)d_in[9];
    const float* dtb   = (const float*)d_in[10];
    const float* Alogs = (const float*)d_in[11];
    const float* Dsv   = (const float*)d_in[12];
    const float* lnw   = (const float*)d_in[13];
    const float* lnb   = (const float*)d_in[14];
    const float* outw[2] = {(const float*)d_in[15], (const float*)d_in[16]};

    float* ws = (float*)d_ws;
    // workspace layout (floats); total 36,175,872 floats = 144.7 MB
    float* xc_raw  = ws + 0;          // 4,194,304  (reused as yz later)
    float* zbuf    = ws + 4194304;    // 4,194,304
    float* xc_conv = ws + 8388608;    // 4,194,304
    float* proj    = ws + 12582912;   // 2,621,440
    float* H0      = ws + 15204352;   // 4,194,304
    float* hend    = ws + 19398656;   // 4,194,304
    float* Pbuf    = ws + 23592960;   // 4,194,304
    float* ysp     = ws + 19398656;   // 16,777,216 (overlays hend+P, dead then)
    float* yz      = xc_raw;
    float* outp    = (float*)d_out;

    for (int s = 0; s < 2; ++s) {
        // in_proj + split + silu(z)
        gemm_ep<1><<<dim3(8, 256), 256, 0, stream>>>(
            xin[s], inw[s], xc_raw, zbuf, 16384, 512, 128);
        // depthwise conv + silu
        dwconv_silu<<<16384, 256, 0, stream>>>(xc_raw, convw[s], convb[s], xc_conv);
        // x_proj (dts_raw | Bs | Cs), all 4 directions
        gemm_ep<0><<<dim3(3, 256), 256, 0, stream>>>(
            xc_conv, xpw, proj, nullptr, 16384, 160, 256);
        // chunked selective scan
        scanA<<<1024, 256, 0, stream>>>(xc_conv, proj, Alogs, dtw, dtb, hend, Pbuf);
        scanB<<<256, 256, 0, stream>>>(hend, Pbuf, H0);
        scanC<<<1024, 256, 0, stream>>>(xc_conv, proj, Alogs, dtw, dtb, Dsv, H0, ysp);
        // merge 4 dirs + LN + gate
        merge_ln<<<16384, 256, 0, stream>>>(ysp, zbuf, lnw, lnb, yz);
        // out_proj
        gemm_ep<0><<<dim3(2, 256), 256, 0, stream>>>(
            yz, outw[s], outp + (size_t)s * 2097152, nullptr, 16384, 128, 256);
    }
}

// Round 2
// 623.738 us; speedup vs baseline: 1.0214x; 1.0214x over previous
//
#include <hip/hip_runtime.h>
#include <math.h>

// Problem constants (B=4, H=W=64, C=128, DI=256, N=16, R=8, K=4)
#define LL   4096     // H*W
#define DDIM 256      // d_inner
#define NCH  128      // number of chunks
#define LCH  32       // chunk length
// B*K*D = 4096 scan channels; B*K*D*N = 65536 states

__device__ __forceinline__ float silu_f(float x) {
    return x / (1.f + __expf(-x));
}
__device__ __forceinline__ float softplus_f(float x) {
    return fmaxf(x, 0.f) + __logf(1.f + __expf(-fabsf(x)));
}
__device__ __forceinline__ int perm_idx(int k, int l) {
    switch (k & 3) {
        case 0: return l;
        case 1: return ((l & 63) << 6) | (l >> 6);
        case 2: return 4095 - l;
        default: { int lr = 4095 - l; return ((lr & 63) << 6) | (lr >> 6); }
    }
}
// dA[n] = e1^(n+1), log-depth mul tree (15 muls, depth<=4)
__device__ __forceinline__ void pow_geom(float e1, float dA[16]) {
    const float e2 = e1 * e1, e4 = e2 * e2, e8 = e4 * e4;
    dA[0] = e1;       dA[1] = e2;       dA[2] = e2 * e1;  dA[3] = e4;
    dA[4] = e4 * e1;  dA[5] = e4 * e2;  dA[6] = e4 * dA[2]; dA[7] = e8;
    dA[8] = e8 * e1;  dA[9] = e8 * e2;  dA[10] = e8 * dA[2]; dA[11] = e8 * e4;
    dA[12] = e8 * dA[4]; dA[13] = e8 * dA[5]; dA[14] = e8 * dA[6]; dA[15] = e8 * e8;
}

// ---------------------------------------------------------------------------
// Generic fp32 tiled GEMM: out[m,n] = sum_k A[m,k] * W[n,k]
// EPI=0: plain store; EPI=1: in_proj split epilogue (xc | silu(z))
// ---------------------------------------------------------------------------
template <int EPI>
__global__ __launch_bounds__(256) void gemm_ep(
    const float* __restrict__ A, const float* __restrict__ W,
    float* __restrict__ out0, float* __restrict__ out1,
    int M, int N, int K) {
    __shared__ float As[16][65];
    __shared__ float Ws[16][65];
    const int tid = threadIdx.x;
    const int bx = blockIdx.x, by = blockIdx.y;
    const int tx = tid & 15, ty = tid >> 4;
    const int lrow = tid >> 2;
    const int lk = (tid & 3) << 2;
    float acc[4][4] = {};
    const float* Ap = A + (size_t)(by * 64 + lrow) * K + lk;
    const int wrow = bx * 64 + lrow;
    const float* Wp = W + (size_t)wrow * K + lk;
    const bool wv = (wrow < N);
    for (int k0 = 0; k0 < K; k0 += 16) {
        float4 av = *(const float4*)(Ap + k0);
        float4 bv = make_float4(0.f, 0.f, 0.f, 0.f);
        if (wv) bv = *(const float4*)(Wp + k0);
        As[lk + 0][lrow] = av.x; As[lk + 1][lrow] = av.y;
        As[lk + 2][lrow] = av.z; As[lk + 3][lrow] = av.w;
        Ws[lk + 0][lrow] = bv.x; Ws[lk + 1][lrow] = bv.y;
        Ws[lk + 2][lrow] = bv.z; Ws[lk + 3][lrow] = bv.w;
        __syncthreads();
        #pragma unroll
        for (int kk = 0; kk < 16; ++kk) {
            float a4[4], b4[4];
            #pragma unroll
            for (int i = 0; i < 4; ++i) a4[i] = As[kk][ty * 4 + i];
            #pragma unroll
            for (int j = 0; j < 4; ++j) b4[j] = Ws[kk][tx * 4 + j];
            #pragma unroll
            for (int i = 0; i < 4; ++i)
                #pragma unroll
                for (int j = 0; j < 4; ++j)
                    acc[i][j] = fmaf(a4[i], b4[j], acc[i][j]);
        }
        __syncthreads();
    }
    #pragma unroll
    for (int i = 0; i < 4; ++i) {
        const int m = by * 64 + ty * 4 + i;
        #pragma unroll
        for (int j = 0; j < 4; ++j) {
            const int nn = bx * 64 + tx * 4 + j;
            if (nn >= N) continue;
            const float v = acc[i][j];
            if (EPI == 0) {
                out0[(size_t)m * N + nn] = v;
            } else {
                if (nn < 256) out0[(size_t)m * 256 + nn] = v;
                else          out1[(size_t)m * 256 + (nn - 256)] = silu_f(v);
            }
        }
    }
}

// ---------------------------------------------------------------------------
// Depthwise 3x3 conv (SAME) + bias + SiLU. Layout (B*L, D) channel-last.
// ---------------------------------------------------------------------------
__global__ __launch_bounds__(256) void dwconv_silu(
    const float* __restrict__ in, const float* __restrict__ w,
    const float* __restrict__ bias, float* __restrict__ out) {
    const int d = threadIdx.x;
    const int bp = blockIdx.x;
    const int b = bp >> 12;
    const int sp = bp & 4095;
    const int h = sp >> 6, wc = sp & 63;
    float acc = bias[d];
    #pragma unroll
    for (int kh = 0; kh < 3; ++kh) {
        const int hh = h + kh - 1;
        if (hh < 0 || hh >= 64) continue;
        #pragma unroll
        for (int kw = 0; kw < 3; ++kw) {
            const int ww = wc + kw - 1;
            if (ww < 0 || ww >= 64) continue;
            acc = fmaf(in[(size_t)(((b << 12) + (hh << 6) + ww)) * DDIM + d],
                       w[d * 9 + kh * 3 + kw], acc);
        }
    }
    out[(size_t)bp * DDIM + d] = silu_f(acc);
}

// ---------------------------------------------------------------------------
// Precompute delta = softplus(dtb + dtw @ proj_dt) for all (b,p,k,d).
// Layout: delta[(b*L+p)*1024 + k*256 + d]
// ---------------------------------------------------------------------------
__global__ __launch_bounds__(256) void dt_pre(
    const float* __restrict__ proj, const float* __restrict__ dtw,
    const float* __restrict__ dtb, float* __restrict__ out) {
    const int d = threadIdx.x;
    const int bp = blockIdx.x;
    const float* prow = proj + (size_t)bp * 160;
    #pragma unroll
    for (int k = 0; k < 4; ++k) {
        const int kd = k * 256 + d;
        float x = dtb[kd];
        const float4 w0 = *(const float4*)(dtw + (size_t)kd * 8);
        const float4 w1 = *(const float4*)(dtw + (size_t)kd * 8 + 4);
        x = fmaf(prow[k * 40 + 0], w0.x, x);
        x = fmaf(prow[k * 40 + 1], w0.y, x);
        x = fmaf(prow[k * 40 + 2], w0.z, x);
        x = fmaf(prow[k * 40 + 3], w0.w, x);
        x = fmaf(prow[k * 40 + 4], w1.x, x);
        x = fmaf(prow[k * 40 + 5], w1.y, x);
        x = fmaf(prow[k * 40 + 6], w1.z, x);
        x = fmaf(prow[k * 40 + 7], w1.w, x);
        out[(size_t)bp * 1024 + kd] = softplus_f(x);
    }
}

// ---------------------------------------------------------------------------
// Scan phase A: per-chunk local scan from h=0. Outputs h_end and decay P.
// blockIdx = bk*NCH + chunk; threads = d.
// ---------------------------------------------------------------------------
template <bool DPRE>
__global__ __launch_bounds__(256) void scanA(
    const float* __restrict__ xc, const float* __restrict__ proj,
    const float* __restrict__ dpre,
    const float* __restrict__ Alogs, const float* __restrict__ dtw,
    const float* __restrict__ dtb,
    float* __restrict__ hend, float* __restrict__ Pout) {
    const int d = threadIdx.x;
    const int blk = blockIdx.x;
    const int c = blk & (NCH - 1);
    const int bk = blk >> 7;
    const int k = bk & 3;
    const int b = bk >> 2;
    const int kd = k * DDIM + d;

    float a[16];
    #pragma unroll
    for (int n = 0; n < 16; ++n) a[n] = -__expf(Alogs[kd * 16 + n]);
    const float a0 = a[0];
    bool geom = true;
    #pragma unroll
    for (int n = 1; n < 16; ++n) {
        const float r = a0 * (float)(n + 1);
        geom = geom && (fabsf(a[n] - r) <= 1e-4f * fabsf(r));
    }
    float w8[8]; float bias = 0.f;
    if (!DPRE) {
        #pragma unroll
        for (int r = 0; r < 8; ++r) w8[r] = dtw[kd * 8 + r];
        bias = dtb[kd];
    }

    float h[16];
    #pragma unroll
    for (int n = 0; n < 16; ++n) h[n] = 0.f;
    float cum = 0.f;
    const int l0 = c * LCH;

    if (geom) {
        for (int t = 0; t < LCH; ++t) {
            const int p = perm_idx(k, l0 + t);
            const int bpp = (b << 12) + p;
            float delta;
            if (DPRE) delta = dpre[((size_t)bpp << 10) + kd];
            else {
                const float* pr0 = proj + (size_t)bpp * 160 + k * 40;
                float x = bias;
                #pragma unroll
                for (int r = 0; r < 8; ++r) x = fmaf(pr0[r], w8[r], x);
                delta = softplus_f(x);
            }
            const float* prB = proj + (size_t)bpp * 160 + k * 40 + 8;
            const float u = xc[(size_t)bpp * DDIM + d];
            const float du = delta * u;
            cum += delta;
            float dA[16];
            pow_geom(__expf(delta * a0), dA);
            #pragma unroll
            for (int n = 0; n < 16; ++n)
                h[n] = fmaf(dA[n], h[n], du * prB[n]);
        }
    } else {
        for (int t = 0; t < LCH; ++t) {
            const int p = perm_idx(k, l0 + t);
            const int bpp = (b << 12) + p;
            float delta;
            if (DPRE) delta = dpre[((size_t)bpp << 10) + kd];
            else {
                const float* pr0 = proj + (size_t)bpp * 160 + k * 40;
                float x = bias;
                #pragma unroll
                for (int r = 0; r < 8; ++r) x = fmaf(pr0[r], w8[r], x);
                delta = softplus_f(x);
            }
            const float* prB = proj + (size_t)bpp * 160 + k * 40 + 8;
            const float u = xc[(size_t)bpp * DDIM + d];
            const float du = delta * u;
            cum += delta;
            #pragma unroll
            for (int n = 0; n < 16; ++n) {
                const float dA = __expf(delta * a[n]);
                h[n] = fmaf(dA, h[n], du * prB[n]);
            }
        }
    }
    const size_t o = ((size_t)c * 4096 + (size_t)bk * DDIM + d) * 16;
    float Pv[16];
    if (geom) pow_geom(__expf(cum * a0), Pv);
    else {
        #pragma unroll
        for (int n = 0; n < 16; ++n) Pv[n] = __expf(cum * a[n]);
    }
    #pragma unroll
    for (int n = 0; n < 16; ++n) { hend[o + n] = h[n]; Pout[o + n] = Pv[n]; }
}

// ---------------------------------------------------------------------------
// Scan phase B: inter-chunk recurrence (NCH steps) over 65536 states.
// ---------------------------------------------------------------------------
__global__ __launch_bounds__(256) void scanB(
    const float* __restrict__ hend, const float* __restrict__ P,
    float* __restrict__ H0) {
    const int tid = blockIdx.x * 256 + threadIdx.x;
    float H = 0.f;
    H0[tid] = 0.f;
    for (int c = 1; c < NCH; ++c) {
        const size_t i = (size_t)(c - 1) * 65536 + tid;
        H = fmaf(P[i], H, hend[i]);
        H0[(size_t)c * 65536 + tid] = H;
    }
}

// ---------------------------------------------------------------------------
// Scan phase C: re-run chunks from true initial state, emit y at spatial pos.
// ---------------------------------------------------------------------------
template <bool DPRE>
__global__ __launch_bounds__(256) void scanC(
    const float* __restrict__ xc, const float* __restrict__ proj,
    const float* __restrict__ dpre,
    const float* __restrict__ Alogs, const float* __restrict__ dtw,
    const float* __restrict__ dtb, const float* __restrict__ Dsv,
    const float* __restrict__ H0, float* __restrict__ ysp) {
    const int d = threadIdx.x;
    const int blk = blockIdx.x;
    const int c = blk & (NCH - 1);
    const int bk = blk >> 7;
    const int k = bk & 3;
    const int b = bk >> 2;
    const int kd = k * DDIM + d;

    float a[16];
    #pragma unroll
    for (int n = 0; n < 16; ++n) a[n] = -__expf(Alogs[kd * 16 + n]);
    const float a0 = a[0];
    bool geom = true;
    #pragma unroll
    for (int n = 1; n < 16; ++n) {
        const float r = a0 * (float)(n + 1);
        geom = geom && (fabsf(a[n] - r) <= 1e-4f * fabsf(r));
    }
    float w8[8]; float bias = 0.f;
    if (!DPRE) {
        #pragma unroll
        for (int r = 0; r < 8; ++r) w8[r] = dtw[kd * 8 + r];
        bias = dtb[kd];
    }
    const float Dd = Dsv[kd];

    float h[16];
    const size_t ho = ((size_t)c * 4096 + (size_t)bk * DDIM + d) * 16;
    #pragma unroll
    for (int n = 0; n < 16; ++n) h[n] = H0[ho + n];

    const int l0 = c * LCH;
    if (geom) {
        for (int t = 0; t < LCH; ++t) {
            const int p = perm_idx(k, l0 + t);
            const int bpp = (b << 12) + p;
            float delta;
            if (DPRE) delta = dpre[((size_t)bpp << 10) + kd];
            else {
                const float* pr0 = proj + (size_t)bpp * 160 + k * 40;
                float x = bias;
                #pragma unroll
                for (int r = 0; r < 8; ++r) x = fmaf(pr0[r], w8[r], x);
                delta = softplus_f(x);
            }
            const float* prB = proj + (size_t)bpp * 160 + k * 40 + 8;
            const float* prC = prB + 16;
            const float u = xc[(size_t)bpp * DDIM + d];
            const float du = delta * u;
            float dA[16];
            pow_geom(__expf(delta * a0), dA);
            float y = 0.f;
            #pragma unroll
            for (int n = 0; n < 16; ++n) {
                h[n] = fmaf(dA[n], h[n], du * prB[n]);
                y = fmaf(h[n], prC[n], y);
            }
            y = fmaf(Dd, u, y);
            ysp[(size_t)((bk << 12) + p) * DDIM + d] = y;
        }
    } else {
        for (int t = 0; t < LCH; ++t) {
            const int p = perm_idx(k, l0 + t);
            const int bpp = (b << 12) + p;
            float delta;
            if (DPRE) delta = dpre[((size_t)bpp << 10) + kd];
            else {
                const float* pr0 = proj + (size_t)bpp * 160 + k * 40;
                float x = bias;
                #pragma unroll
                for (int r = 0; r < 8; ++r) x = fmaf(pr0[r], w8[r], x);
                delta = softplus_f(x);
            }
            const float* prB = proj + (size_t)bpp * 160 + k * 40 + 8;
            const float* prC = prB + 16;
            const float u = xc[(size_t)bpp * DDIM + d];
            const float du = delta * u;
            float y = 0.f;
            #pragma unroll
            for (int n = 0; n < 16; ++n) {
                const float dA = __expf(delta * a[n]);
                h[n] = fmaf(dA, h[n], du * prB[n]);
                y = fmaf(h[n], prC[n], y);
            }
            y = fmaf(Dd, u, y);
            ysp[(size_t)((bk << 12) + p) * DDIM + d] = y;
        }
    }
}

// ---------------------------------------------------------------------------
// Merge 4 directions + LayerNorm(D) + gate with z.
// ---------------------------------------------------------------------------
__global__ __launch_bounds__(256) void merge_ln(
    const float* __restrict__ ysp, const float* __restrict__ z,
    const float* __restrict__ lnw, const float* __restrict__ lnb,
    float* __restrict__ yz) {
    const int d = threadIdx.x;
    const int bp = blockIdx.x;
    const int b = bp >> 12;
    const int p = bp & 4095;
    float v = 0.f;
    #pragma unroll
    for (int k = 0; k < 4; ++k)
        v += ysp[(size_t)((((b << 2) + k) << 12) + p) * DDIM + d];

    __shared__ float red[4];
    float s = v;
    #pragma unroll
    for (int o = 32; o > 0; o >>= 1) s += __shfl_xor(s, o);
    const int wave = threadIdx.x >> 6;
    if ((threadIdx.x & 63) == 0) red[wave] = s;
    __syncthreads();
    const float mu = (red[0] + red[1] + red[2] + red[3]) * (1.f / 256.f);
    __syncthreads();
    const float dv = v - mu;
    float s2 = dv * dv;
    #pragma unroll
    for (int o = 32; o > 0; o >>= 1) s2 += __shfl_xor(s2, o);
    if ((threadIdx.x & 63) == 0) red[wave] = s2;
    __syncthreads();
    const float var = (red[0] + red[1] + red[2] + red[3]) * (1.f / 256.f);
    const float y = dv * rsqrtf(var + 1e-5f) * lnw[d] + lnb[d];
    yz[(size_t)bp * DDIM + d] = y * z[(size_t)bp * DDIM + d];
}

// ---------------------------------------------------------------------------
extern "C" void kernel_launch(void* const* d_in, const int* in_sizes, int n_in,
                              void* d_out, int out_size, void* d_ws, size_t ws_size,
                              hipStream_t stream) {
    const float* xin[2]   = {(const float*)d_in[0],  (const float*)d_in[1]};
    const float* inw[2]   = {(const float*)d_in[2],  (const float*)d_in[3]};
    const float* convw[2] = {(const float*)d_in[4],  (const float*)d_in[6]};
    const float* convb[2] = {(const float*)d_in[5],  (const float*)d_in[7]};
    const float* xpw   = (const float*)d_in[8];
    const float* dtw   = (const float*)d_in[9];
    const float* dtb   = (const float*)d_in[10];
    const float* Alogs = (const float*)d_in[11];
    const float* Dsv   = (const float*)d_in[12];
    const float* lnw   = (const float*)d_in[13];
    const float* lnb   = (const float*)d_in[14];
    const float* outw[2] = {(const float*)d_in[15], (const float*)d_in[16]};

    float* ws = (float*)d_ws;
    // workspace layout (floats):
    float* xc_raw  = ws + 0;          // 4,194,304  (later yz)
    float* zbuf    = ws + 4194304;    // 4,194,304
    float* xc_conv = ws + 8388608;    // 4,194,304
    float* proj    = ws + 12582912;   // 2,621,440
    float* hend    = ws + 15204352;   // 8,388,608  (128 chunks x 65536)
    float* Pbuf    = ws + 23592960;   // 8,388,608
    float* H0      = ws + 31981568;   // 8,388,608   -> total 40,370,176 floats
    float* ysp     = ws + 15204352;   // 16,777,216 overlays hend+P (dead after scanB)
    float* dpre    = ws + 40370176;   // 16,777,216 (optional; needs 228.6MB total)
    float* yz      = xc_raw;
    float* outp    = (float*)d_out;

    const bool use_dpre = ws_size >= (size_t)(40370176 + 16777216) * 4;

    for (int s = 0; s < 2; ++s) {
        gemm_ep<1><<<dim3(8, 256), 256, 0, stream>>>(
            xin[s], inw[s], xc_raw, zbuf, 16384, 512, 128);
        dwconv_silu<<<16384, 256, 0, stream>>>(xc_raw, convw[s], convb[s], xc_conv);
        gemm_ep<0><<<dim3(3, 256), 256, 0, stream>>>(
            xc_conv, xpw, proj, nullptr, 16384, 160, 256);
        if (use_dpre) {
            dt_pre<<<16384, 256, 0, stream>>>(proj, dtw, dtb, dpre);
            scanA<true><<<16 * NCH, 256, 0, stream>>>(
                xc_conv, proj, dpre, Alogs, dtw, dtb, hend, Pbuf);
            scanB<<<256, 256, 0, stream>>>(hend, Pbuf, H0);
            scanC<true><<<16 * NCH, 256, 0, stream>>>(
                xc_conv, proj, dpre, Alogs, dtw, dtb, Dsv, H0, ysp);
        } else {
            scanA<false><<<16 * NCH, 256, 0, stream>>>(
                xc_conv, proj, nullptr, Alogs, dtw, dtb, hend, Pbuf);
            scanB<<<256, 256, 0, stream>>>(hend, Pbuf, H0);
            scanC<false><<<16 * NCH, 256, 0, stream>>>(
                xc_conv, proj, nullptr, Alogs, dtw, dtb, Dsv, H0, ysp);
        }
        merge_ln<<<16384, 256, 0, stream>>>(ysp, zbuf, lnw, lnb, yz);
        gemm_ep<0><<<dim3(2, 256), 256, 0, stream>>>(
            yz, outw[s], outp + (size_t)s * 2097152, nullptr, 16384, 128, 256);
    }
}

// Round 3
// 463.927 us; speedup vs baseline: 1.3732x; 1.3445x over previous
//
#include <hip/hip_runtime.h>
#include <hip/hip_bf16.h>
#include <math.h>

// Problem constants (B=4, H=W=64, C=128, DI=256, N=16, R=8, K=4)
#define DDIM 256
#define NCH  128
#define LCH  32

typedef __attribute__((ext_vector_type(8))) short bf8_t;
typedef __attribute__((ext_vector_type(4))) float f32x4;
typedef __attribute__((ext_vector_type(8))) unsigned short u16x8;

__device__ __forceinline__ float silu_f(float x) {
    return x / (1.f + __expf(-x));
}
__device__ __forceinline__ float softplus_f(float x) {
    return fmaxf(x, 0.f) + __logf(1.f + __expf(-fabsf(x)));
}
__device__ __forceinline__ unsigned short f2b(float x) {
    union { __hip_bfloat16 h; unsigned short u; } v;
    v.h = __float2bfloat16(x);
    return v.u;
}
__device__ __forceinline__ int perm_idx(int k, int l) {
    switch (k & 3) {
        case 0: return l;
        case 1: return ((l & 63) << 6) | (l >> 6);
        case 2: return 4095 - l;
        default: { int lr = 4095 - l; return ((lr & 63) << 6) | (lr >> 6); }
    }
}
// dA[n] = e1^(n+1), log-depth mul tree
__device__ __forceinline__ void pow_geom(float e1, float dA[16]) {
    const float e2 = e1 * e1, e4 = e2 * e2, e8 = e4 * e4;
    dA[0] = e1;       dA[1] = e2;       dA[2] = e2 * e1;  dA[3] = e4;
    dA[4] = e4 * e1;  dA[5] = e4 * e2;  dA[6] = e4 * dA[2]; dA[7] = e8;
    dA[8] = e8 * e1;  dA[9] = e8 * e2;  dA[10] = e8 * dA[2]; dA[11] = e8 * e4;
    dA[12] = e8 * dA[4]; dA[13] = e8 * dA[5]; dA[14] = e8 * dA[6]; dA[15] = e8 * e8;
}

// ---------------------------------------------------------------------------
// fp32 -> bf16 conversion, 8 elems/thread, n8 = n/8 groups (n % 8 == 0)
// ---------------------------------------------------------------------------
__global__ __launch_bounds__(256) void cvt_bf16(
    const float* __restrict__ in, unsigned short* __restrict__ out, int n8) {
    const int i = blockIdx.x * 256 + threadIdx.x;
    if (i >= n8) return;
    const float4 a = ((const float4*)in)[i * 2];
    const float4 b = ((const float4*)in)[i * 2 + 1];
    u16x8 r;
    r[0] = f2b(a.x); r[1] = f2b(a.y); r[2] = f2b(a.z); r[3] = f2b(a.w);
    r[4] = f2b(b.x); r[5] = f2b(b.y); r[6] = f2b(b.z); r[7] = f2b(b.w);
    *(u16x8*)(out + (size_t)i * 8) = r;
}

// ---------------------------------------------------------------------------
// bf16 MFMA GEMM: out[m,n] = sum_k A[m,k] * W[n,k]  (A: MxK, W: NxK bf16)
// 128x128 tile, 4 waves (2x2), 16x16x32 MFMA, BK=32, fp32 out.
// EPI=0: out0[m*N+n] plain. EPI=1 (in_proj, N=512): n<256 -> out0 (xc),
//        n>=256 -> out1 = silu (z).  Requires M%128==0, K%32==0.
// ---------------------------------------------------------------------------
template <int EPI>
__global__ __launch_bounds__(256) void gemm_bf(
    const unsigned short* __restrict__ A, const unsigned short* __restrict__ W,
    float* __restrict__ out0, float* __restrict__ out1, int N, int K) {
    __shared__ unsigned short As[128][40];
    __shared__ unsigned short Bs[128][40];
    const int tid = threadIdx.x;
    const int lane = tid & 63;
    const int wid = tid >> 6;
    const int wr = wid >> 1, wc = wid & 1;
    const int m0 = blockIdx.y << 7, n0 = blockIdx.x << 7;
    const int r = lane & 15, g = lane >> 4;
    f32x4 acc[4][4];
    #pragma unroll
    for (int i = 0; i < 4; ++i)
        #pragma unroll
        for (int j = 0; j < 4; ++j) acc[i][j] = (f32x4){0.f, 0.f, 0.f, 0.f};
    const int row0 = tid >> 2;       // 0..63
    const int cc = (tid & 3) << 3;   // 0,8,16,24

    for (int k0 = 0; k0 < K; k0 += 32) {
        #pragma unroll
        for (int h = 0; h < 2; ++h) {
            const int row = row0 + (h << 6);
            const u16x8 va = *(const u16x8*)(A + (size_t)(m0 + row) * K + k0 + cc);
            *(u16x8*)(&As[row][cc]) = va;
            const int nrow = n0 + row;
            u16x8 vb = (u16x8){0, 0, 0, 0, 0, 0, 0, 0};
            if (nrow < N) vb = *(const u16x8*)(W + (size_t)nrow * K + k0 + cc);
            *(u16x8*)(&Bs[row][cc]) = vb;
        }
        __syncthreads();
        bf8_t af[4], bfr[4];
        #pragma unroll
        for (int i = 0; i < 4; ++i)
            af[i] = *(const bf8_t*)(&As[(wr << 6) + (i << 4) + r][g << 3]);
        #pragma unroll
        for (int j = 0; j < 4; ++j)
            bfr[j] = *(const bf8_t*)(&Bs[(wc << 6) + (j << 4) + r][g << 3]);
        #pragma unroll
        for (int i = 0; i < 4; ++i)
            #pragma unroll
            for (int j = 0; j < 4; ++j)
                acc[i][j] = __builtin_amdgcn_mfma_f32_16x16x32_bf16(
                    af[i], bfr[j], acc[i][j], 0, 0, 0);
        __syncthreads();
    }
    // epilogue: C/D layout col=lane&15, row=(lane>>4)*4+reg
    #pragma unroll
    for (int i = 0; i < 4; ++i) {
        const int mrow = m0 + (wr << 6) + (i << 4) + (g << 2);
        #pragma unroll
        for (int j = 0; j < 4; ++j) {
            const int col = n0 + (wc << 6) + (j << 4) + r;
            if (EPI == 0 && col >= N) continue;
            #pragma unroll
            for (int q = 0; q < 4; ++q) {
                const float v = acc[i][j][q];
                const int mm = mrow + q;
                if (EPI == 0) {
                    out0[(size_t)mm * N + col] = v;
                } else {
                    if (col < 256) out0[((size_t)mm << 8) + col] = v;
                    else out1[((size_t)mm << 8) + (col - 256)] = silu_f(v);
                }
            }
        }
    }
}

// ---------------------------------------------------------------------------
// Depthwise 3x3 conv (SAME) + bias + SiLU; dual write fp32 + bf16.
// ---------------------------------------------------------------------------
__global__ __launch_bounds__(256) void dwconv_silu(
    const float* __restrict__ in, const float* __restrict__ w,
    const float* __restrict__ bias, float* __restrict__ outf,
    unsigned short* __restrict__ outb) {
    const int d = threadIdx.x;
    const int bp = blockIdx.x;
    const int b = bp >> 12;
    const int sp = bp & 4095;
    const int h = sp >> 6, wc = sp & 63;
    float acc = bias[d];
    #pragma unroll
    for (int kh = 0; kh < 3; ++kh) {
        const int hh = h + kh - 1;
        if (hh < 0 || hh >= 64) continue;
        #pragma unroll
        for (int kw = 0; kw < 3; ++kw) {
            const int ww = wc + kw - 1;
            if (ww < 0 || ww >= 64) continue;
            acc = fmaf(in[(size_t)(((b << 12) + (hh << 6) + ww)) * DDIM + d],
                       w[d * 9 + kh * 3 + kw], acc);
        }
    }
    const float s = silu_f(acc);
    outf[(size_t)bp * DDIM + d] = s;
    outb[(size_t)bp * DDIM + d] = f2b(s);
}

// ---------------------------------------------------------------------------
// Scan phase A: per-chunk local scan from h=0. Outputs h_end and decay P.
// blockIdx = bk*NCH + chunk; threads = d.
// ---------------------------------------------------------------------------
__global__ __launch_bounds__(256) void scanA(
    const float* __restrict__ xc, const float* __restrict__ proj,
    const float* __restrict__ Alogs, const float* __restrict__ dtw,
    const float* __restrict__ dtb,
    float* __restrict__ hend, float* __restrict__ Pout) {
    const int d = threadIdx.x;
    const int blk = blockIdx.x;
    const int c = blk & (NCH - 1);
    const int bk = blk >> 7;
    const int k = bk & 3;
    const int b = bk >> 2;
    const int kd = k * DDIM + d;

    float a[16];
    #pragma unroll
    for (int n = 0; n < 16; ++n) a[n] = -__expf(Alogs[kd * 16 + n]);
    const float a0 = a[0];
    bool geom = true;
    #pragma unroll
    for (int n = 1; n < 16; ++n) {
        const float rr = a0 * (float)(n + 1);
        geom = geom && (fabsf(a[n] - rr) <= 1e-4f * fabsf(rr));
    }
    float w8[8];
    #pragma unroll
    for (int r = 0; r < 8; ++r) w8[r] = dtw[kd * 8 + r];
    const float bias = dtb[kd];

    float h[16];
    #pragma unroll
    for (int n = 0; n < 16; ++n) h[n] = 0.f;
    float cum = 0.f;
    const int l0 = c * LCH;

    if (geom) {
        for (int t = 0; t < LCH; ++t) {
            const int p = perm_idx(k, l0 + t);
            const int bpp = (b << 12) + p;
            const float* pr0 = proj + (size_t)bpp * 160 + k * 40;
            float x = bias;
            #pragma unroll
            for (int r = 0; r < 8; ++r) x = fmaf(pr0[r], w8[r], x);
            const float delta = softplus_f(x);
            const float u = xc[(size_t)bpp * DDIM + d];
            const float du = delta * u;
            cum += delta;
            float dA[16];
            pow_geom(__expf(delta * a0), dA);
            #pragma unroll
            for (int n = 0; n < 16; ++n)
                h[n] = fmaf(dA[n], h[n], du * pr0[8 + n]);
        }
    } else {
        for (int t = 0; t < LCH; ++t) {
            const int p = perm_idx(k, l0 + t);
            const int bpp = (b << 12) + p;
            const float* pr0 = proj + (size_t)bpp * 160 + k * 40;
            float x = bias;
            #pragma unroll
            for (int r = 0; r < 8; ++r) x = fmaf(pr0[r], w8[r], x);
            const float delta = softplus_f(x);
            const float u = xc[(size_t)bpp * DDIM + d];
            const float du = delta * u;
            cum += delta;
            #pragma unroll
            for (int n = 0; n < 16; ++n) {
                const float dA = __expf(delta * a[n]);
                h[n] = fmaf(dA, h[n], du * pr0[8 + n]);
            }
        }
    }
    const size_t o = ((size_t)c * 4096 + (size_t)bk * DDIM + d) * 16;
    float Pv[16];
    if (geom) pow_geom(__expf(cum * a0), Pv);
    else {
        #pragma unroll
        for (int n = 0; n < 16; ++n) Pv[n] = __expf(cum * a[n]);
    }
    #pragma unroll
    for (int n = 0; n < 16; ++n) { hend[o + n] = h[n]; Pout[o + n] = Pv[n]; }
}

// ---------------------------------------------------------------------------
// Scan phase B: inter-chunk recurrence (NCH steps) over 65536 states.
// ---------------------------------------------------------------------------
__global__ __launch_bounds__(256) void scanB(
    const float* __restrict__ hend, const float* __restrict__ P,
    float* __restrict__ H0) {
    const int tid = blockIdx.x * 256 + threadIdx.x;
    float H = 0.f;
    H0[tid] = 0.f;
    for (int c = 1; c < NCH; ++c) {
        const size_t i = (size_t)(c - 1) * 65536 + tid;
        H = fmaf(P[i], H, hend[i]);
        H0[(size_t)c * 65536 + tid] = H;
    }
}

// ---------------------------------------------------------------------------
// Scan phase C: re-run chunks from true initial state, emit y at spatial pos.
// ---------------------------------------------------------------------------
__global__ __launch_bounds__(256) void scanC(
    const float* __restrict__ xc, const float* __restrict__ proj,
    const float* __restrict__ Alogs, const float* __restrict__ dtw,
    const float* __restrict__ dtb, const float* __restrict__ Dsv,
    const float* __restrict__ H0, float* __restrict__ ysp) {
    const int d = threadIdx.x;
    const int blk = blockIdx.x;
    const int c = blk & (NCH - 1);
    const int bk = blk >> 7;
    const int k = bk & 3;
    const int b = bk >> 2;
    const int kd = k * DDIM + d;

    float a[16];
    #pragma unroll
    for (int n = 0; n < 16; ++n) a[n] = -__expf(Alogs[kd * 16 + n]);
    const float a0 = a[0];
    bool geom = true;
    #pragma unroll
    for (int n = 1; n < 16; ++n) {
        const float rr = a0 * (float)(n + 1);
        geom = geom && (fabsf(a[n] - rr) <= 1e-4f * fabsf(rr));
    }
    float w8[8];
    #pragma unroll
    for (int r = 0; r < 8; ++r) w8[r] = dtw[kd * 8 + r];
    const float bias = dtb[kd];
    const float Dd = Dsv[kd];

    float h[16];
    const size_t ho = ((size_t)c * 4096 + (size_t)bk * DDIM + d) * 16;
    #pragma unroll
    for (int n = 0; n < 16; ++n) h[n] = H0[ho + n];

    const int l0 = c * LCH;
    if (geom) {
        for (int t = 0; t < LCH; ++t) {
            const int p = perm_idx(k, l0 + t);
            const int bpp = (b << 12) + p;
            const float* pr0 = proj + (size_t)bpp * 160 + k * 40;
            float x = bias;
            #pragma unroll
            for (int r = 0; r < 8; ++r) x = fmaf(pr0[r], w8[r], x);
            const float delta = softplus_f(x);
            const float u = xc[(size_t)bpp * DDIM + d];
            const float du = delta * u;
            float dA[16];
            pow_geom(__expf(delta * a0), dA);
            float y = 0.f;
            #pragma unroll
            for (int n = 0; n < 16; ++n) {
                h[n] = fmaf(dA[n], h[n], du * pr0[8 + n]);
                y = fmaf(h[n], pr0[24 + n], y);
            }
            y = fmaf(Dd, u, y);
            ysp[(size_t)((bk << 12) + p) * DDIM + d] = y;
        }
    } else {
        for (int t = 0; t < LCH; ++t) {
            const int p = perm_idx(k, l0 + t);
            const int bpp = (b << 12) + p;
            const float* pr0 = proj + (size_t)bpp * 160 + k * 40;
            float x = bias;
            #pragma unroll
            for (int r = 0; r < 8; ++r) x = fmaf(pr0[r], w8[r], x);
            const float delta = softplus_f(x);
            const float u = xc[(size_t)bpp * DDIM + d];
            const float du = delta * u;
            float y = 0.f;
            #pragma unroll
            for (int n = 0; n < 16; ++n) {
                const float dA = __expf(delta * a[n]);
                h[n] = fmaf(dA, h[n], du * pr0[8 + n]);
                y = fmaf(h[n], pr0[24 + n], y);
            }
            y = fmaf(Dd, u, y);
            ysp[(size_t)((bk << 12) + p) * DDIM + d] = y;
        }
    }
}

// ---------------------------------------------------------------------------
// Merge 4 directions + LayerNorm(D) + gate with z. Writes bf16 for out_proj.
// ---------------------------------------------------------------------------
__global__ __launch_bounds__(256) void merge_ln(
    const float* __restrict__ ysp, const float* __restrict__ z,
    const float* __restrict__ lnw, const float* __restrict__ lnb,
    unsigned short* __restrict__ yzb) {
    const int d = threadIdx.x;
    const int bp = blockIdx.x;
    const int b = bp >> 12;
    const int p = bp & 4095;
    float v = 0.f;
    #pragma unroll
    for (int k = 0; k < 4; ++k)
        v += ysp[(size_t)((((b << 2) + k) << 12) + p) * DDIM + d];

    __shared__ float red[4];
    float s = v;
    #pragma unroll
    for (int o = 32; o > 0; o >>= 1) s += __shfl_xor(s, o);
    const int wave = threadIdx.x >> 6;
    if ((threadIdx.x & 63) == 0) red[wave] = s;
    __syncthreads();
    const float mu = (red[0] + red[1] + red[2] + red[3]) * (1.f / 256.f);
    __syncthreads();
    const float dv = v - mu;
    float s2 = dv * dv;
    #pragma unroll
    for (int o = 32; o > 0; o >>= 1) s2 += __shfl_xor(s2, o);
    if ((threadIdx.x & 63) == 0) red[wave] = s2;
    __syncthreads();
    const float var = (red[0] + red[1] + red[2] + red[3]) * (1.f / 256.f);
    const float y = dv * rsqrtf(var + 1e-5f) * lnw[d] + lnb[d];
    yzb[(size_t)bp * DDIM + d] = f2b(y * z[(size_t)bp * DDIM + d]);
}

// ---------------------------------------------------------------------------
extern "C" void kernel_launch(void* const* d_in, const int* in_sizes, int n_in,
                              void* d_out, int out_size, void* d_ws, size_t ws_size,
                              hipStream_t stream) {
    const float* xin[2]   = {(const float*)d_in[0],  (const float*)d_in[1]};
    const float* inw[2]   = {(const float*)d_in[2],  (const float*)d_in[3]};
    const float* convw[2] = {(const float*)d_in[4],  (const float*)d_in[6]};
    const float* convb[2] = {(const float*)d_in[5],  (const float*)d_in[7]};
    const float* xpw   = (const float*)d_in[8];
    const float* dtw   = (const float*)d_in[9];
    const float* dtb   = (const float*)d_in[10];
    const float* Alogs = (const float*)d_in[11];
    const float* Dsv   = (const float*)d_in[12];
    const float* lnw   = (const float*)d_in[13];
    const float* lnb   = (const float*)d_in[14];
    const float* outw[2] = {(const float*)d_in[15], (const float*)d_in[16]};

    float* ws = (float*)d_ws;
    // fp32 regions (total 40,370,176 floats = 161.5 MB, same as round 2):
    float* xc_raw  = ws + 0;          // 4,194,304   steps 2-3 (dead after conv)
    float* zbuf    = ws + 4194304;    // 4,194,304   steps 2-6
    float* xc_conv = ws + 8388608;    // 4,194,304   steps 3-5
    float* proj    = ws + 12582912;   // 2,621,440   steps 4-5
    float* hend    = ws + 15204352;   // 8,388,608   scanA->scanB
    float* Pbuf    = ws + 23592960;   // 8,388,608   scanA->scanB
    float* H0      = ws + 31981568;   // 8,388,608   scanB->scanC
    float* ysp     = ws + 15204352;   // 16,777,216  overlays hend+P (dead post-scanB)
    // bf16 overlays in dead regions:
    unsigned short* yzbf    = (unsigned short*)(ws + 0);         // xc_raw region, steps 6-7
    unsigned short* wbf_out = (unsigned short*)(ws + 2097152);   // xc_raw region, steps 3.5-7
    unsigned short* xcbf    = (unsigned short*)(ws + 23592960);  // Pbuf region, steps 3-4
    unsigned short* xbf     = (unsigned short*)(ws + 31981568);  // H0 region, steps 1-2
    unsigned short* wbf_in  = (unsigned short*)(ws + 31981568 + 1048576); // steps 0-2
    unsigned short* wbf_xp  = (unsigned short*)(ws + 31981568 + 1081344); // steps 0-4
    float* outp = (float*)d_out;

    for (int s = 0; s < 2; ++s) {
        // 0/1: weight + input conversions to bf16
        cvt_bf16<<<32, 256, 0, stream>>>(inw[s], wbf_in, 8192);     // 512x128
        cvt_bf16<<<20, 256, 0, stream>>>(xpw, wbf_xp, 5120);        // 160x256
        cvt_bf16<<<1024, 256, 0, stream>>>(xin[s], xbf, 262144);    // 16384x128
        // 2: in_proj (M=16384, N=512, K=128) + split + silu(z)
        gemm_bf<1><<<dim3(4, 128), 256, 0, stream>>>(
            xbf, wbf_in, xc_raw, zbuf, 512, 128);
        // 3: depthwise conv + silu (fp32 for scan, bf16 for x_proj)
        dwconv_silu<<<16384, 256, 0, stream>>>(xc_raw, convw[s], convb[s],
                                               xc_conv, xcbf);
        // 3.5: out_proj weight conversion (xc_raw now dead)
        cvt_bf16<<<16, 256, 0, stream>>>(outw[s], wbf_out, 4096);   // 128x256
        // 4: x_proj (M=16384, N=160, K=256)
        gemm_bf<0><<<dim3(2, 128), 256, 0, stream>>>(
            xcbf, wbf_xp, proj, nullptr, 160, 256);
        // 5: chunked selective scan
        scanA<<<16 * NCH, 256, 0, stream>>>(xc_conv, proj, Alogs, dtw, dtb,
                                            hend, Pbuf);
        scanB<<<256, 256, 0, stream>>>(hend, Pbuf, H0);
        scanC<<<16 * NCH, 256, 0, stream>>>(xc_conv, proj, Alogs, dtw, dtb,
                                            Dsv, H0, ysp);
        // 6: merge 4 dirs + LN + gate -> bf16
        merge_ln<<<16384, 256, 0, stream>>>(ysp, zbuf, lnw, lnb, yzbf);
        // 7: out_proj (M=16384, N=128, K=256)
        gemm_bf<0><<<dim3(1, 128), 256, 0, stream>>>(
            yzbf, wbf_out, outp + (size_t)s * 2097152, nullptr, 128, 256);
    }
}

// Round 4
// 461.070 us; speedup vs baseline: 1.3817x; 1.0062x over previous
//
#include <hip/hip_runtime.h>
#include <hip/hip_bf16.h>
#include <math.h>

// Problem constants (B=4, H=W=64, C=128, DI=256, N=16, R=8, K=4)
#define DDIM 256
#define NCH  128
#define LCH  32

typedef __attribute__((ext_vector_type(8))) short bf8_t;
typedef __attribute__((ext_vector_type(4))) float f32x4;
typedef __attribute__((ext_vector_type(8))) unsigned short u16x8;

__device__ __forceinline__ float silu_f(float x) {
    return x / (1.f + __expf(-x));
}
__device__ __forceinline__ float softplus_f(float x) {
    return fmaxf(x, 0.f) + __logf(1.f + __expf(-fabsf(x)));
}
__device__ __forceinline__ unsigned short f2b(float x) {
    union { __hip_bfloat16 h; unsigned short u; } v;
    v.h = __float2bfloat16(x);
    return v.u;
}
__device__ __forceinline__ int perm_idx(int k, int l) {
    switch (k & 3) {
        case 0: return l;
        case 1: return ((l & 63) << 6) | (l >> 6);
        case 2: return 4095 - l;
        default: { int lr = 4095 - l; return ((lr & 63) << 6) | (lr >> 6); }
    }
}
// dA[n] = e1^(n+1), log-depth mul tree
__device__ __forceinline__ void pow_geom(float e1, float dA[16]) {
    const float e2 = e1 * e1, e4 = e2 * e2, e8 = e4 * e4;
    dA[0] = e1;       dA[1] = e2;       dA[2] = e2 * e1;  dA[3] = e4;
    dA[4] = e4 * e1;  dA[5] = e4 * e2;  dA[6] = e4 * dA[2]; dA[7] = e8;
    dA[8] = e8 * e1;  dA[9] = e8 * e2;  dA[10] = e8 * dA[2]; dA[11] = e8 * e4;
    dA[12] = e8 * dA[4]; dA[13] = e8 * dA[5]; dA[14] = e8 * dA[6]; dA[15] = e8 * e8;
}

// ---------------------------------------------------------------------------
// fp32 -> bf16 conversion (weights only now)
// ---------------------------------------------------------------------------
__global__ __launch_bounds__(256) void cvt_bf16(
    const float* __restrict__ in, unsigned short* __restrict__ out, int n8) {
    const int i = blockIdx.x * 256 + threadIdx.x;
    if (i >= n8) return;
    const float4 a = ((const float4*)in)[i * 2];
    const float4 b = ((const float4*)in)[i * 2 + 1];
    u16x8 r;
    r[0] = f2b(a.x); r[1] = f2b(a.y); r[2] = f2b(a.z); r[3] = f2b(a.w);
    r[4] = f2b(b.x); r[5] = f2b(b.y); r[6] = f2b(b.z); r[7] = f2b(b.w);
    *(u16x8*)(out + (size_t)i * 8) = r;
}

// ---------------------------------------------------------------------------
// bf16 MFMA GEMM: out[m,n] = sum_k A[m,k] * W[n,k]  (W: NxK bf16)
// A is bf16 (AF32=false, ptr A) or fp32 (AF32=true, ptr Af, converted in
// staging). 128x128 tile, 4 waves (2x2), 16x16x32 MFMA, BK=32, fp32 out.
// EPI=0: plain store. EPI=1 (in_proj, N=512): n<256 -> xc, n>=256 -> silu -> z
// ---------------------------------------------------------------------------
template <int EPI, bool AF32>
__global__ __launch_bounds__(256) void gemm_bf(
    const unsigned short* __restrict__ A, const float* __restrict__ Af,
    const unsigned short* __restrict__ W,
    float* __restrict__ out0, float* __restrict__ out1, int N, int K) {
    __shared__ unsigned short As[128][40];
    __shared__ unsigned short Bs[128][40];
    const int tid = threadIdx.x;
    const int lane = tid & 63;
    const int wid = tid >> 6;
    const int wr = wid >> 1, wc = wid & 1;
    const int m0 = blockIdx.y << 7, n0 = blockIdx.x << 7;
    const int r = lane & 15, g = lane >> 4;
    f32x4 acc[4][4];
    #pragma unroll
    for (int i = 0; i < 4; ++i)
        #pragma unroll
        for (int j = 0; j < 4; ++j) acc[i][j] = (f32x4){0.f, 0.f, 0.f, 0.f};
    const int row0 = tid >> 2;       // 0..63
    const int cc = (tid & 3) << 3;   // 0,8,16,24

    for (int k0 = 0; k0 < K; k0 += 32) {
        #pragma unroll
        for (int h = 0; h < 2; ++h) {
            const int row = row0 + (h << 6);
            u16x8 va;
            if (AF32) {
                const float* ap = Af + (size_t)(m0 + row) * K + k0 + cc;
                const float4 a0 = *(const float4*)ap;
                const float4 a1 = *(const float4*)(ap + 4);
                va[0] = f2b(a0.x); va[1] = f2b(a0.y);
                va[2] = f2b(a0.z); va[3] = f2b(a0.w);
                va[4] = f2b(a1.x); va[5] = f2b(a1.y);
                va[6] = f2b(a1.z); va[7] = f2b(a1.w);
            } else {
                va = *(const u16x8*)(A + (size_t)(m0 + row) * K + k0 + cc);
            }
            *(u16x8*)(&As[row][cc]) = va;
            const int nrow = n0 + row;
            u16x8 vb = (u16x8){0, 0, 0, 0, 0, 0, 0, 0};
            if (nrow < N) vb = *(const u16x8*)(W + (size_t)nrow * K + k0 + cc);
            *(u16x8*)(&Bs[row][cc]) = vb;
        }
        __syncthreads();
        bf8_t af[4], bfr[4];
        #pragma unroll
        for (int i = 0; i < 4; ++i)
            af[i] = *(const bf8_t*)(&As[(wr << 6) + (i << 4) + r][g << 3]);
        #pragma unroll
        for (int j = 0; j < 4; ++j)
            bfr[j] = *(const bf8_t*)(&Bs[(wc << 6) + (j << 4) + r][g << 3]);
        #pragma unroll
        for (int i = 0; i < 4; ++i)
            #pragma unroll
            for (int j = 0; j < 4; ++j)
                acc[i][j] = __builtin_amdgcn_mfma_f32_16x16x32_bf16(
                    af[i], bfr[j], acc[i][j], 0, 0, 0);
        __syncthreads();
    }
    // epilogue: C/D layout col=lane&15, row=(lane>>4)*4+reg
    #pragma unroll
    for (int i = 0; i < 4; ++i) {
        const int mrow = m0 + (wr << 6) + (i << 4) + (g << 2);
        #pragma unroll
        for (int j = 0; j < 4; ++j) {
            const int col = n0 + (wc << 6) + (j << 4) + r;
            if (EPI == 0 && col >= N) continue;
            #pragma unroll
            for (int q = 0; q < 4; ++q) {
                const float v = acc[i][j][q];
                const int mm = mrow + q;
                if (EPI == 0) {
                    out0[(size_t)mm * N + col] = v;
                } else {
                    if (col < 256) out0[((size_t)mm << 8) + col] = v;
                    else out1[((size_t)mm << 8) + (col - 256)] = silu_f(v);
                }
            }
        }
    }
}

// ---------------------------------------------------------------------------
// Depthwise 3x3 conv (SAME) + bias + SiLU; dual write fp32 + bf16.
// ---------------------------------------------------------------------------
__global__ __launch_bounds__(256) void dwconv_silu(
    const float* __restrict__ in, const float* __restrict__ w,
    const float* __restrict__ bias, float* __restrict__ outf,
    unsigned short* __restrict__ outb) {
    const int d = threadIdx.x;
    const int bp = blockIdx.x;
    const int b = bp >> 12;
    const int sp = bp & 4095;
    const int h = sp >> 6, wc = sp & 63;
    float acc = bias[d];
    #pragma unroll
    for (int kh = 0; kh < 3; ++kh) {
        const int hh = h + kh - 1;
        if (hh < 0 || hh >= 64) continue;
        #pragma unroll
        for (int kw = 0; kw < 3; ++kw) {
            const int ww = wc + kw - 1;
            if (ww < 0 || ww >= 64) continue;
            acc = fmaf(in[(size_t)(((b << 12) + (hh << 6) + ww)) * DDIM + d],
                       w[d * 9 + kh * 3 + kw], acc);
        }
    }
    const float s = silu_f(acc);
    outf[(size_t)bp * DDIM + d] = s;
    outb[(size_t)bp * DDIM + d] = f2b(s);
}

// ---------------------------------------------------------------------------
// Scan phase A: per-chunk local scan from h=0. Outputs h_end and cum-delta.
// blockIdx = bk*NCH + chunk; threads = d. (P is NOT stored: scanB recomputes
// it from cumΔ since prod exp(δ a) = exp(a Σδ) exactly.)
// ---------------------------------------------------------------------------
__global__ __launch_bounds__(256) void scanA(
    const float* __restrict__ xc, const float* __restrict__ proj,
    const float* __restrict__ Alogs, const float* __restrict__ dtw,
    const float* __restrict__ dtb,
    float* __restrict__ hend, float* __restrict__ cumd) {
    const int d = threadIdx.x;
    const int blk = blockIdx.x;
    const int c = blk & (NCH - 1);
    const int bk = blk >> 7;
    const int k = bk & 3;
    const int b = bk >> 2;
    const int kd = (k << 8) + d;

    float a[16];
    #pragma unroll
    for (int n = 0; n < 16; ++n) a[n] = -__expf(Alogs[kd * 16 + n]);
    const float a0 = a[0];
    bool geom = true;
    #pragma unroll
    for (int n = 1; n < 16; ++n) {
        const float rr = a0 * (float)(n + 1);
        geom = geom && (fabsf(a[n] - rr) <= 1e-4f * fabsf(rr));
    }
    float w8[8];
    #pragma unroll
    for (int r = 0; r < 8; ++r) w8[r] = dtw[kd * 8 + r];
    const float bias = dtb[kd];

    float h[16];
    #pragma unroll
    for (int n = 0; n < 16; ++n) h[n] = 0.f;
    float cum = 0.f;
    const int l0 = c * LCH;

    if (geom) {
        for (int t = 0; t < LCH; ++t) {
            const int p = perm_idx(k, l0 + t);
            const int bpp = (b << 12) + p;
            const float* pr0 = proj + (size_t)bpp * 160 + k * 40;
            float x = bias;
            #pragma unroll
            for (int r = 0; r < 8; ++r) x = fmaf(pr0[r], w8[r], x);
            const float delta = softplus_f(x);
            const float u = xc[(size_t)bpp * DDIM + d];
            const float du = delta * u;
            cum += delta;
            float dA[16];
            pow_geom(__expf(delta * a0), dA);
            #pragma unroll
            for (int n = 0; n < 16; ++n)
                h[n] = fmaf(dA[n], h[n], du * pr0[8 + n]);
        }
    } else {
        for (int t = 0; t < LCH; ++t) {
            const int p = perm_idx(k, l0 + t);
            const int bpp = (b << 12) + p;
            const float* pr0 = proj + (size_t)bpp * 160 + k * 40;
            float x = bias;
            #pragma unroll
            for (int r = 0; r < 8; ++r) x = fmaf(pr0[r], w8[r], x);
            const float delta = softplus_f(x);
            const float u = xc[(size_t)bpp * DDIM + d];
            const float du = delta * u;
            cum += delta;
            #pragma unroll
            for (int n = 0; n < 16; ++n) {
                const float dA = __expf(delta * a[n]);
                h[n] = fmaf(dA, h[n], du * pr0[8 + n]);
            }
        }
    }
    const size_t o = ((size_t)c * 4096 + (size_t)bk * DDIM + d) * 16;
    #pragma unroll
    for (int n = 0; n < 16; ++n) hend[o + n] = h[n];
    cumd[(size_t)(c * 16 + bk) * DDIM + d] = cum;
}

// ---------------------------------------------------------------------------
// Scan phase B: inter-chunk recurrence (NCH steps) over 65536 states.
// P recomputed as exp(cumΔ * a) (exact identity, works for any A).
// ---------------------------------------------------------------------------
__global__ __launch_bounds__(256) void scanB(
    const float* __restrict__ hend, const float* __restrict__ cumd,
    const float* __restrict__ Alogs, float* __restrict__ H0) {
    const int tid = blockIdx.x * 256 + threadIdx.x;
    const int n = tid & 15;
    const int d = (tid >> 4) & 255;
    const int bk = tid >> 12;
    const int k = bk & 3;
    const float a = -__expf(Alogs[(size_t)(((k << 8) + d)) * 16 + n]);
    float H = 0.f;
    H0[tid] = 0.f;
    for (int c = 1; c < NCH; ++c) {
        const size_t i = (size_t)(c - 1) * 65536 + tid;
        const float P = __expf(cumd[(size_t)((c - 1) * 16 + bk) * DDIM + d] * a);
        H = fmaf(P, H, hend[i]);
        H0[(size_t)c * 65536 + tid] = H;
    }
}

// ---------------------------------------------------------------------------
// Scan phase C chunk worker: run one chunk of direction k from its true
// initial state. EMIT=0: store y into ybuf[t][d] (thread-private column).
// EMIT=1: emit ybuf[31-t][d] + y to ysp plane at spatial position.
// ---------------------------------------------------------------------------
template <int EMIT>
__device__ __forceinline__ void scanC_chunk(
    const int k, const int chunk, const int b, const int d,
    const float* __restrict__ xc, const float* __restrict__ proj,
    const float* __restrict__ Alogs, const float* __restrict__ dtw,
    const float* __restrict__ dtb, const float* __restrict__ Dsv,
    const float* __restrict__ H0, float* __restrict__ ysp,
    float (*ybuf)[256], const size_t planeBase) {
    const int kd = (k << 8) + d;
    const int bk = (b << 2) + k;

    float a[16];
    #pragma unroll
    for (int n = 0; n < 16; ++n) a[n] = -__expf(Alogs[kd * 16 + n]);
    const float a0 = a[0];
    bool geom = true;
    #pragma unroll
    for (int n = 1; n < 16; ++n) {
        const float rr = a0 * (float)(n + 1);
        geom = geom && (fabsf(a[n] - rr) <= 1e-4f * fabsf(rr));
    }
    float w8[8];
    #pragma unroll
    for (int r = 0; r < 8; ++r) w8[r] = dtw[kd * 8 + r];
    const float bias = dtb[kd];
    const float Dd = Dsv[kd];

    float h[16];
    const size_t ho = ((size_t)chunk * 4096 + (size_t)bk * DDIM + d) * 16;
    #pragma unroll
    for (int n = 0; n < 16; ++n) h[n] = H0[ho + n];

    const int l0 = chunk * LCH;
    if (geom) {
        for (int t = 0; t < LCH; ++t) {
            const int p = perm_idx(k, l0 + t);
            const int bpp = (b << 12) + p;
            const float* pr0 = proj + (size_t)bpp * 160 + k * 40;
            float x = bias;
            #pragma unroll
            for (int r = 0; r < 8; ++r) x = fmaf(pr0[r], w8[r], x);
            const float delta = softplus_f(x);
            const float u = xc[(size_t)bpp * DDIM + d];
            const float du = delta * u;
            float dA[16];
            pow_geom(__expf(delta * a0), dA);
            float y = 0.f;
            #pragma unroll
            for (int n = 0; n < 16; ++n) {
                h[n] = fmaf(dA[n], h[n], du * pr0[8 + n]);
                y = fmaf(h[n], pr0[24 + n], y);
            }
            y = fmaf(Dd, u, y);
            if (EMIT == 0) ybuf[t][d] = y;
            else ysp[planeBase + (size_t)p * DDIM + d] = y + ybuf[31 - t][d];
        }
    } else {
        for (int t = 0; t < LCH; ++t) {
            const int p = perm_idx(k, l0 + t);
            const int bpp = (b << 12) + p;
            const float* pr0 = proj + (size_t)bpp * 160 + k * 40;
            float x = bias;
            #pragma unroll
            for (int r = 0; r < 8; ++r) x = fmaf(pr0[r], w8[r], x);
            const float delta = softplus_f(x);
            const float u = xc[(size_t)bpp * DDIM + d];
            const float du = delta * u;
            float y = 0.f;
            #pragma unroll
            for (int n = 0; n < 16; ++n) {
                const float dA = __expf(delta * a[n]);
                h[n] = fmaf(dA, h[n], du * pr0[8 + n]);
                y = fmaf(h[n], pr0[24 + n], y);
            }
            y = fmaf(Dd, u, y);
            if (EMIT == 0) ybuf[t][d] = y;
            else ysp[planeBase + (size_t)p * DDIM + d] = y + ybuf[31 - t][d];
        }
    }
}

// ---------------------------------------------------------------------------
// Scan phase C, pair-fused: block handles (k=pair, chunk c) then
// (k=pair+2, chunk NCH-1-c). The two cover the same 32-position window
// (perm(k+2,l) = perm(k,4095-l)), so the pair's y-sum is emitted directly:
// ysp has only 2 planes. ybuf columns are thread-private -> no barrier.
// blockIdx = (b*2+pair)*NCH + c
// ---------------------------------------------------------------------------
__global__ __launch_bounds__(256) void scanC2(
    const float* __restrict__ xc, const float* __restrict__ proj,
    const float* __restrict__ Alogs, const float* __restrict__ dtw,
    const float* __restrict__ dtb, const float* __restrict__ Dsv,
    const float* __restrict__ H0, float* __restrict__ ysp) {
    __shared__ float ybuf[LCH][256];
    const int d = threadIdx.x;
    const int blk = blockIdx.x;
    const int c = blk & (NCH - 1);
    const int bp2 = blk >> 7;
    const int pair = bp2 & 1;
    const int b = bp2 >> 1;
    const size_t planeBase = (size_t)bp2 << 20;  // bp2 * 4096 * 256
    scanC_chunk<0>(pair, c, b, d, xc, proj, Alogs, dtw, dtb, Dsv, H0,
                   ysp, ybuf, planeBase);
    scanC_chunk<1>(pair + 2, NCH - 1 - c, b, d, xc, proj, Alogs, dtw, dtb,
                   Dsv, H0, ysp, ybuf, planeBase);
}

// ---------------------------------------------------------------------------
// Merge 2 pair-planes + LayerNorm(D) + gate with z. Writes bf16.
// ---------------------------------------------------------------------------
__global__ __launch_bounds__(256) void merge_ln(
    const float* __restrict__ ysp, const float* __restrict__ z,
    const float* __restrict__ lnw, const float* __restrict__ lnb,
    unsigned short* __restrict__ yzb) {
    const int d = threadIdx.x;
    const int bp = blockIdx.x;
    const int b = bp >> 12;
    const int p = bp & 4095;
    const float v = ysp[(((size_t)(b << 1) << 12) + p) * DDIM + d]
                  + ysp[(((size_t)((b << 1) + 1) << 12) + p) * DDIM + d];

    __shared__ float red[4];
    float s = v;
    #pragma unroll
    for (int o = 32; o > 0; o >>= 1) s += __shfl_xor(s, o);
    const int wave = threadIdx.x >> 6;
    if ((threadIdx.x & 63) == 0) red[wave] = s;
    __syncthreads();
    const float mu = (red[0] + red[1] + red[2] + red[3]) * (1.f / 256.f);
    __syncthreads();
    const float dv = v - mu;
    float s2 = dv * dv;
    #pragma unroll
    for (int o = 32; o > 0; o >>= 1) s2 += __shfl_xor(s2, o);
    if ((threadIdx.x & 63) == 0) red[wave] = s2;
    __syncthreads();
    const float var = (red[0] + red[1] + red[2] + red[3]) * (1.f / 256.f);
    const float y = dv * rsqrtf(var + 1e-5f) * lnw[d] + lnb[d];
    yzb[(size_t)bp * DDIM + d] = f2b(y * z[(size_t)bp * DDIM + d]);
}

// ---------------------------------------------------------------------------
extern "C" void kernel_launch(void* const* d_in, const int* in_sizes, int n_in,
                              void* d_out, int out_size, void* d_ws, size_t ws_size,
                              hipStream_t stream) {
    const float* xin[2]   = {(const float*)d_in[0],  (const float*)d_in[1]};
    const float* inw[2]   = {(const float*)d_in[2],  (const float*)d_in[3]};
    const float* convw[2] = {(const float*)d_in[4],  (const float*)d_in[6]};
    const float* convb[2] = {(const float*)d_in[5],  (const float*)d_in[7]};
    const float* xpw   = (const float*)d_in[8];
    const float* dtw   = (const float*)d_in[9];
    const float* dtb   = (const float*)d_in[10];
    const float* Alogs = (const float*)d_in[11];
    const float* Dsv   = (const float*)d_in[12];
    const float* lnw   = (const float*)d_in[13];
    const float* lnb   = (const float*)d_in[14];
    const float* outw[2] = {(const float*)d_in[15], (const float*)d_in[16]};

    float* ws = (float*)d_ws;
    // fp32 regions (float offsets), total footprint 161.5 MB (unchanged):
    float* xc_raw  = ws + 0;          // 4,194,304  in_proj out (dead after conv)
    float* zbuf    = ws + 4194304;    // 4,194,304  silu(z), lives to merge_ln
    float* xc_conv = ws + 8388608;    // 4,194,304  conv out fp32 (scan input)
    float* proj    = ws + 12582912;   // 2,621,440  x_proj out
    float* hend    = ws + 15204352;   // 8,388,608  scanA -> scanB
    float* cumd    = ws + 23592960;   //   524,288  scanA -> scanB
    float* H0      = ws + 31981568;   // 8,388,608  scanB -> scanC
    float* ysp     = ws + 15204352;   // 8,388,608  2 planes (overlays dead hend)
    // bf16 overlays in dead/free regions:
    unsigned short* yzbf    = (unsigned short*)(ws + 0);         // xc_raw region
    unsigned short* wbf_out = (unsigned short*)(ws + 2097152);   // xc_raw region
    unsigned short* xcbf    = (unsigned short*)(ws + 24117248);  // after cumd
    unsigned short* wbf_in  = (unsigned short*)(ws + 26214400);  // free gap
    unsigned short* wbf_xp  = (unsigned short*)(ws + 26247168);  // free gap
    float* outp = (float*)d_out;

    for (int s = 0; s < 2; ++s) {
        // weight conversions to bf16 (tiny)
        cvt_bf16<<<32, 256, 0, stream>>>(inw[s], wbf_in, 8192);   // 512x128
        cvt_bf16<<<20, 256, 0, stream>>>(xpw, wbf_xp, 5120);      // 160x256
        // in_proj (M=16384, N=512, K=128), A fp32 converted in staging
        gemm_bf<1, true><<<dim3(4, 128), 256, 0, stream>>>(
            nullptr, xin[s], wbf_in, xc_raw, zbuf, 512, 128);
        // depthwise conv + silu (fp32 for scan, bf16 for x_proj)
        dwconv_silu<<<16384, 256, 0, stream>>>(xc_raw, convw[s], convb[s],
                                               xc_conv, xcbf);
        // out_proj weight conversion (xc_raw region now dead)
        cvt_bf16<<<16, 256, 0, stream>>>(outw[s], wbf_out, 4096); // 128x256
        // x_proj (M=16384, N=160, K=256)
        gemm_bf<0, false><<<dim3(2, 128), 256, 0, stream>>>(
            xcbf, nullptr, wbf_xp, proj, nullptr, 160, 256);
        // chunked selective scan
        scanA<<<16 * NCH, 256, 0, stream>>>(xc_conv, proj, Alogs, dtw, dtb,
                                            hend, cumd);
        scanB<<<256, 256, 0, stream>>>(hend, cumd, Alogs, H0);
        scanC2<<<8 * NCH, 256, 0, stream>>>(xc_conv, proj, Alogs, dtw, dtb,
                                            Dsv, H0, ysp);
        // merge pair-planes + LN + gate -> bf16
        merge_ln<<<16384, 256, 0, stream>>>(ysp, zbuf, lnw, lnb, yzbf);
        // out_proj (M=16384, N=128, K=256)
        gemm_bf<0, false><<<dim3(1, 128), 256, 0, stream>>>(
            yzbf, nullptr, wbf_out, outp + (size_t)s * 2097152, nullptr,
            128, 256);
    }
}